// Round 12
// baseline (429.108 us; speedup 1.0000x reference)
//
#include <hip/hip_runtime.h>

typedef __attribute__((ext_vector_type(8))) short short8;
typedef __attribute__((ext_vector_type(4))) float floatx4;

#define NCH 294         // chunks per layer
#define CH 8192         // edges per chunk
#define NB 196          // coarse buckets (1024 keys each)
#define NKP 200704      // padded key count (NB*1024)

__device__ __forceinline__ unsigned short f2bf(float f) {
  unsigned u = __float_as_uint(f);
  u += 0x7FFFu + ((u >> 16) & 1u);
  return (unsigned short)(u >> 16);
}
__device__ __forceinline__ float blo(unsigned x) { return __uint_as_float(x << 16); }
__device__ __forceinline__ float bhi(unsigned x) { return __uint_as_float(x & 0xFFFF0000u); }

// ---- fused prep (feat->bf16, W transposes) + per-chunk bucket histogram ----
__global__ __launch_bounds__(1024) void prep_count_k(
    const float* __restrict__ feat, const float* __restrict__ W1,
    const float* __restrict__ W2, const int* __restrict__ ed1,
    const int* __restrict__ ed2, unsigned short* __restrict__ featb,
    unsigned short* __restrict__ w1t, unsigned short* __restrict__ w2t,
    int* __restrict__ ghist, int* __restrict__ done) {
  __shared__ int h[NB];
  if (blockIdx.x == 0 && threadIdx.x == 0) *done = 0;  // reset flag for scanb
  if (blockIdx.x < 2 * NCH) {            // count role
    int tid = threadIdx.x;
    int layer = blockIdx.x >= NCH;
    int c = blockIdx.x - layer * NCH;
    const int* ed = layer ? ed2 : ed1;
    if (tid < NB) h[tid] = 0;
    __syncthreads();
    int j0 = c * CH;
    for (int it = 0; it < CH / 1024; ++it) {
      int j = j0 + it * 1024 + tid;
      if (j < 2400000) atomicAdd(&h[(ed[j] * 4 + j / 800000) >> 10], 1);
    }
    __syncthreads();
    if (tid < NB) ghist[(layer * NB + tid) * NCH + c] = h[tid];
  } else {                               // prep role
    int tid = (blockIdx.x - 2 * NCH) * 1024 + threadIdx.x;
    if (tid < 1600000) {
      float4 v = ((const float4*)feat)[tid];
      ushort4 o;
      o.x = f2bf(v.x); o.y = f2bf(v.y); o.z = f2bf(v.z); o.w = f2bf(v.w);
      ((ushort4*)featb)[tid] = o;
    } else if (tid < 1600000 + 49152) {
      int t = tid - 1600000;
      int r = t >> 14, rem = t & 16383, n = rem >> 7, k = rem & 127;
      w1t[t] = f2bf(W1[(r << 14) + (k << 7) + n]);
    } else if (tid < 1600000 + 49152 + 24576) {
      int t = tid - 1649152;
      int r = t >> 13, rem = t & 8191, n = rem >> 7, k = rem & 127;
      w2t[t] = f2bf(W2[(r << 13) + (k << 6) + n]);
    }
  }
}

// ---- per-(layer,bucket) scan of chunk counts + fused bucket-base scan
// (last-block pattern: final block scans btot -> bbase, saves a launch) ----
__global__ __launch_bounds__(320) void scanb_k(int* __restrict__ ghist,
                                               int* __restrict__ btot,
                                               int* __restrict__ bbase,
                                               int* __restrict__ done) {
  __shared__ int wsum[5];
  __shared__ int amLast;
  int t = threadIdx.x, lane = t & 63, w = t >> 6;
  int base = blockIdx.x * NCH;
  int v = (t < NCH) ? ghist[base + t] : 0;
  int inc = v;
#pragma unroll
  for (int o = 1; o < 64; o <<= 1) {
    int u = __shfl_up(inc, o);
    if (lane >= o) inc += u;
  }
  if (lane == 63) wsum[w] = inc;
  __syncthreads();
  int woff = 0;
#pragma unroll
  for (int k = 0; k < 5; ++k) if (k < w) woff += wsum[k];
  if (t < NCH) ghist[base + t] = woff + inc - v;
  if (t == 319) btot[blockIdx.x] = woff + inc;
  __threadfence();
  __syncthreads();
  if (t == 0) amLast = (atomicAdd(done, 1) == 2 * NB - 1);
  __syncthreads();
  if (amLast && t < 64) {
    int carry = 0;
    for (int g0 = 0; g0 < 448; g0 += 64) {
      int i = g0 + t;
      int vv = (i < 2 * NB) ? btot[i] : 0;
      int ic = vv;
#pragma unroll
      for (int o = 1; o < 64; o <<= 1) {
        int u = __shfl_up(ic, o);
        if (t >= o) ic += u;
      }
      if (i < 2 * NB) bbase[i] = carry + ic - vv;
      carry += __shfl(ic, 63);
    }
    if (t == 0) bbase[2 * NB] = carry;
  }
}

// ---- chunk-local LDS-cursor scatter -> sorted[] (src | within-bucket-key<<16) ----
// Plain stores: cell-sequential scatter NEEDS L2 write-combining (R10 lesson).
__global__ __launch_bounds__(1024) void scatter_k(
    const int* __restrict__ es1, const int* __restrict__ ed1,
    const int* __restrict__ es2, const int* __restrict__ ed2,
    const int* __restrict__ ghist, const int* __restrict__ bbase,
    unsigned* __restrict__ sorted) {
  __shared__ int cur[NB];
  int tid = threadIdx.x;
  int layer = blockIdx.x >= NCH;
  int c = blockIdx.x - layer * NCH;
  const int* es = layer ? es2 : es1;
  const int* ed = layer ? ed2 : ed1;
  if (tid < NB)
    cur[tid] = bbase[layer * NB + tid] + ghist[(layer * NB + tid) * NCH + c];
  __syncthreads();
  int j0 = c * CH;
  for (int it = 0; it < CH / 1024; ++it) {
    int j = j0 + it * 1024 + tid;
    if (j < 2400000) {
      int key = ed[j] * 4 + j / 800000;
      int pos = atomicAdd(&cur[key >> 10], 1);
      sorted[pos] = (unsigned)es[j] | ((unsigned)(key & 1023) << 16);
    }
  }
}

// ---- per-bucket micro-sort: bucket-grouped -> key-sorted ushort srcs + off/cnt ----
__global__ __launch_bounds__(512) void sortb_k(
    const int* __restrict__ bbase, const unsigned* __restrict__ sorted,
    unsigned short* __restrict__ sorted2, int* __restrict__ offk,
    int* __restrict__ cntk) {
  __shared__ int hist[1024], cur[1024];
  int tid = threadIdx.x;
  int layer = blockIdx.x >= NB;
  int b = blockIdx.x - layer * NB;
  int start = bbase[blockIdx.x];
  int end = bbase[blockIdx.x + 1];
  hist[tid] = 0;
  hist[tid + 512] = 0;
  __syncthreads();
  for (int e = start + tid; e < end; e += 512)
    atomicAdd(&hist[sorted[e] >> 16], 1);
  __syncthreads();
  if (tid < 64) {
    int carry = 0;
    for (int g0 = 0; g0 < 1024; g0 += 64) {
      int h = hist[g0 + tid];
      int inc = h;
#pragma unroll
      for (int o = 1; o < 64; o <<= 1) {
        int u = __shfl_up(inc, o);
        if (tid >= o) inc += u;
      }
      int excl = carry + inc - h;
      cur[g0 + tid] = excl;
      int lb = layer * NKP + (b << 10) + g0 + tid;
      offk[lb] = start + excl;
      cntk[lb] = h;
      carry += __shfl(inc, 63);
    }
  }
  __syncthreads();
  for (int e = start + tid; e < end; e += 512) {
    unsigned v = sorted[e];
    int p = atomicAdd(&cur[v >> 16], 1);
    sorted2[start + p] = (unsigned short)(v & 0xFFFFu);
  }
}

// ---- layer-1 agg: wave per node, 3 etype streams INTERLEAVED for MLP
// (up to 6 independent gathers in flight per step; 2 edges per vmem instr) ----
__global__ __launch_bounds__(256) void agg1_k(
    const int* __restrict__ offk, const int* __restrict__ cntk,
    const unsigned short* __restrict__ sorted2,
    const uint2* __restrict__ fb2, uint2* __restrict__ s1m2) {
  int lane = threadIdx.x & 63;
  int half = lane >> 5, l32 = lane & 31;
  int v = blockIdx.x * 4 + (threadIdx.x >> 6);
  if (v >= 50000) return;
  const uint2* fb = fb2 + l32;
  int base[3], n[3];
#pragma unroll
  for (int r = 0; r < 3; ++r) {
    base[r] = offk[v * 4 + r];
    n[r] = cntk[v * 4 + r];
  }
  float a[3][4];
#pragma unroll
  for (int r = 0; r < 3; ++r)
#pragma unroll
    for (int d = 0; d < 4; ++d) a[r][d] = 0.f;
  int nmax = n[0] > n[1] ? n[0] : n[1];
  nmax = nmax > n[2] ? nmax : n[2];

  for (int jb = 0; jb < nmax; jb += 64) {
    int my[3], pr[3], od[3];
    int maxp = 0;
#pragma unroll
    for (int r = 0; r < 3; ++r) {
      int m = n[r] - jb;
      m = m < 0 ? 0 : (m > 64 ? 64 : m);
      my[r] = (lane < m) ? (int)sorted2[base[r] + jb + lane] : 0;
      pr[r] = m >> 1;
      od[r] = m & 1;
      maxp = pr[r] > maxp ? pr[r] : maxp;
    }
    int k2 = 0;
    for (; k2 + 2 <= maxp; k2 += 2) {
      uint2 p0[3], p1[3];
      bool c0[3], c1[3];
#pragma unroll
      for (int r = 0; r < 3; ++r) {
        c0[r] = (k2 < pr[r]);
        c1[r] = (k2 + 1 < pr[r]);
        int i0 = __shfl(my[r], 2 * k2 + half);
        int j1 = 2 * k2 + 2 + half; j1 = j1 > 63 ? 63 : j1;
        int i1 = __shfl(my[r], j1);
        if (c0[r]) p0[r] = fb[i0 << 5];
        if (c1[r]) p1[r] = fb[i1 << 5];
      }
#pragma unroll
      for (int r = 0; r < 3; ++r) {
        if (c0[r]) {
          a[r][0] += blo(p0[r].x); a[r][1] += bhi(p0[r].x);
          a[r][2] += blo(p0[r].y); a[r][3] += bhi(p0[r].y);
        }
        if (c1[r]) {
          a[r][0] += blo(p1[r].x); a[r][1] += bhi(p1[r].x);
          a[r][2] += blo(p1[r].y); a[r][3] += bhi(p1[r].y);
        }
      }
    }
    for (; k2 < maxp; ++k2) {
      uint2 p[3]; bool c[3];
#pragma unroll
      for (int r = 0; r < 3; ++r) {
        c[r] = (k2 < pr[r]);
        int i = __shfl(my[r], 2 * k2 + half);
        if (c[r]) p[r] = fb[i << 5];
      }
#pragma unroll
      for (int r = 0; r < 3; ++r) if (c[r]) {
        a[r][0] += blo(p[r].x); a[r][1] += bhi(p[r].x);
        a[r][2] += blo(p[r].y); a[r][3] += bhi(p[r].y);
      }
    }
#pragma unroll
    for (int r = 0; r < 3; ++r) if (od[r]) {
      int i = __shfl(my[r], pr[r] << 1);
      if (half == 0) {
        uint2 p = fb[i << 5];
        a[r][0] += blo(p.x); a[r][1] += bhi(p.x);
        a[r][2] += blo(p.y); a[r][3] += bhi(p.y);
      }
    }
  }
#pragma unroll
  for (int r = 0; r < 3; ++r) {
    float a0 = a[r][0], a1 = a[r][1], a2 = a[r][2], a3 = a[r][3];
    a0 += __shfl_xor(a0, 32); a1 += __shfl_xor(a1, 32);
    a2 += __shfl_xor(a2, 32); a3 += __shfl_xor(a3, 32);
    float inv = 1.0f / fmaxf((float)n[r], 1.0f);
    if (half == 0) {
      uint2 o;
      o.x = ((unsigned)f2bf(a1 * inv) << 16) | (unsigned)f2bf(a0 * inv);
      o.y = ((unsigned)f2bf(a3 * inv) << 16) | (unsigned)f2bf(a2 * inv);
      s1m2[(r * 50000 + v) * 32 + l32] = o;
    }
  }
}

// ---- fused GEMM1+GEMM2, persistent weights in registers, grid-stride M ----
__global__ __launch_bounds__(512) void gemm12_k(
    const unsigned short* __restrict__ s1m, const int* __restrict__ cntk,
    const unsigned short* __restrict__ w1t, const float* __restrict__ b1,
    const unsigned short* __restrict__ w2t, const float* __restrict__ b2,
    unsigned short* __restrict__ wh2) {
  __shared__ unsigned short hs[2][16 * 136];
  int lane = threadIdx.x & 63;
  int w = threadIdx.x >> 6;             // 0..7
  int m16 = lane & 15, kg = lane >> 4;
  int orow = kg << 2;

  short8 B1[12];
#pragma unroll
  for (int ks = 0; ks < 12; ++ks) {
    int r = ks >> 2;
    int k0 = ((ks & 3) << 5) + (kg << 3);
    int n = (w << 4) + m16;
    B1[ks] = *(const short8*)(w1t + (r << 14) + (n << 7) + k0);
  }
  int fa = w, fb = w + 8;
  int cola = (fa << 4) + m16, colb = (fb << 4) + m16;
  int ra = cola >> 6, c0a = cola & 63;
  int rb = colb >> 6, c0b = colb & 63;
  short8 B2a[4], B2b[4];
#pragma unroll
  for (int ks = 0; ks < 4; ++ks) {
    int k0 = (ks << 5) + (kg << 3);
    B2a[ks] = *(const short8*)(w2t + (ra << 13) + (c0a << 7) + k0);
    if (w < 4)
      B2b[ks] = *(const short8*)(w2t + (rb << 13) + (c0b << 7) + k0);
  }
  int col1 = (w << 4) + m16;
  float bb0 = b1[col1], bb1 = b1[128 + col1], bb2 = b1[256 + col1];
  float bva = b2[(ra << 6) + c0a];
  float bvb = (w < 4) ? b2[(rb << 6) + c0b] : 0.f;

  const floatx4 fzero = {0.f, 0.f, 0.f, 0.f};
  int p = 0;
  for (int t = blockIdx.x; t < 3125; t += 512) {
    int rbase = t << 4;
    int anode = rbase + m16;
    floatx4 acc1 = fzero;
#pragma unroll
    for (int ks = 0; ks < 12; ++ks) {
      int r = ks >> 2;
      int k0 = ((ks & 3) << 5) + (kg << 3);
      short8 af = *(const short8*)(s1m + ((r * 50000 + anode) << 7) + k0);
      acc1 = __builtin_amdgcn_mfma_f32_16x16x32_bf16(af, B1[ks], acc1, 0, 0, 0);
    }
#pragma unroll
    for (int reg = 0; reg < 4; ++reg) {
      int nd = rbase + orow + reg;
      float v = acc1[reg] + (cntk[nd * 4 + 0] ? bb0 : 0.f) +
                (cntk[nd * 4 + 1] ? bb1 : 0.f) + (cntk[nd * 4 + 2] ? bb2 : 0.f);
      v = (v >= 0.f) ? v : 0.01f * v;
      hs[p][(orow + reg) * 136 + col1] = f2bf(v);
    }
    __syncthreads();

    floatx4 acc2a = fzero, acc2b = fzero;
#pragma unroll
    for (int ks = 0; ks < 4; ++ks) {
      int k0 = (ks << 5) + (kg << 3);
      short8 af = *(const short8*)(&hs[p][m16 * 136 + k0]);
      acc2a = __builtin_amdgcn_mfma_f32_16x16x32_bf16(af, B2a[ks], acc2a, 0, 0, 0);
      if (w < 4)
        acc2b = __builtin_amdgcn_mfma_f32_16x16x32_bf16(af, B2b[ks], acc2b, 0, 0, 0);
    }
#pragma unroll
    for (int reg = 0; reg < 4; ++reg) {
      int nd = rbase + orow + reg;
      wh2[((ra * 50000 + nd) << 6) + c0a] = f2bf(acc2a[reg] + bva);
      if (w < 4)
        wh2[((rb * 50000 + nd) << 6) + c0b] = f2bf(acc2b[reg] + bvb);
    }
    p ^= 1;
  }
}

// ---- layer-2 agg + final: wave per node, 4 edges per vmem instr (uint2/16 lanes) ----
__global__ __launch_bounds__(256) void agg2f_k(
    const int* __restrict__ offk, const int* __restrict__ cntk,
    const unsigned short* __restrict__ sorted2,
    const uint2* __restrict__ wh2q, float* __restrict__ out) {
  int lane = threadIdx.x & 63;
  int q = lane >> 4, l16 = lane & 15;
  int v = blockIdx.x * 4 + (threadIdx.x >> 6);
  if (v >= 50000) return;
  const uint2* wb = wh2q + l16;
  float o0 = 0.f, o1 = 0.f, o2 = 0.f, o3 = 0.f;
#pragma unroll
  for (int r = 0; r < 3; ++r) {
    int key = NKP + v * 4 + r;
    int base = offk[key], n = cntk[key];
    const uint2* wbr = wb + ((r * 50000) << 4);
    float a0 = 0.f, a1 = 0.f, a2 = 0.f, a3 = 0.f;
    for (int jb = 0; jb < n; jb += 64) {
      int m = n - jb; if (m > 64) m = 64;
      int my = (lane < m) ? (int)sorted2[base + jb + lane] : 0;
      int k = 0;
      for (; k + 16 <= m; k += 16) {
        int i0 = __shfl(my, k + q);
        int i1 = __shfl(my, k + 4 + q);
        int i2 = __shfl(my, k + 8 + q);
        int i3 = __shfl(my, k + 12 + q);
        uint2 p0 = wbr[i0 << 4], p1 = wbr[i1 << 4];
        uint2 p2 = wbr[i2 << 4], p3 = wbr[i3 << 4];
        a0 += blo(p0.x) + blo(p1.x) + blo(p2.x) + blo(p3.x);
        a1 += bhi(p0.x) + bhi(p1.x) + bhi(p2.x) + bhi(p3.x);
        a2 += blo(p0.y) + blo(p1.y) + blo(p2.y) + blo(p3.y);
        a3 += bhi(p0.y) + bhi(p1.y) + bhi(p2.y) + bhi(p3.y);
      }
      for (; k + 4 <= m; k += 4) {
        uint2 p = wbr[__shfl(my, k + q) << 4];
        a0 += blo(p.x); a1 += bhi(p.x); a2 += blo(p.y); a3 += bhi(p.y);
      }
      if (k < m) {
        int rem = m - k;
        int i0 = __shfl(my, k + (q < rem ? q : 0));
        if (q < rem) {
          uint2 p = wbr[i0 << 4];
          a0 += blo(p.x); a1 += bhi(p.x); a2 += blo(p.y); a3 += bhi(p.y);
        }
      }
    }
    float inv = 1.0f / fmaxf((float)n, 1.0f);
    o0 += a0 * inv; o1 += a1 * inv; o2 += a2 * inv; o3 += a3 * inv;
  }
  o0 += __shfl_xor(o0, 16); o0 += __shfl_xor(o0, 32);
  o1 += __shfl_xor(o1, 16); o1 += __shfl_xor(o1, 32);
  o2 += __shfl_xor(o2, 16); o2 += __shfl_xor(o2, 32);
  o3 += __shfl_xor(o3, 16); o3 += __shfl_xor(o3, 32);
  if (q == 0) {
    float4 o; o.x = o0; o.y = o1; o.z = o2; o.w = o3;
    ((float4*)out)[(v << 4) + l16] = o;
  }
}

extern "C" void kernel_launch(void* const* d_in, const int* in_sizes, int n_in,
                              void* d_out, int out_size, void* d_ws, size_t ws_size,
                              hipStream_t stream) {
  const float* feat = (const float*)d_in[0];
  const float* W1   = (const float*)d_in[1];
  const float* b1   = (const float*)d_in[2];
  const float* W2   = (const float*)d_in[3];
  const float* b2   = (const float*)d_in[4];
  const int* es1 = (const int*)d_in[5];
  const int* ed1 = (const int*)d_in[6];
  const int* es2 = (const int*)d_in[7];
  const int* ed2 = (const int*)d_in[8];

  char* ws = (char*)d_ws;
  int* ghist           = (int*)(ws + 0);             // 2*196*294 ints = 460,992 B
  int* btot            = (int*)(ws + 462848);        // 392 ints
  int* bbase           = (int*)(ws + 464448);        // 393 ints
  int* done            = (int*)(ws + 466048);        // 1 int
  unsigned* sorted     = (unsigned*)(ws + 466176);   // 19.2 MB
  unsigned short* sorted2 = (unsigned short*)(ws + 19666176); // 9.6 MB
  int* offk            = (int*)(ws + 29266176);      // 2*200704 ints
  int* cntk            = (int*)(ws + 30871808);      // 2*200704 ints
  unsigned short* featb = (unsigned short*)(ws + 32477440);  // 12.8 MB
  unsigned short* s1m   = (unsigned short*)(ws + 45277440);  // 38.4 MB
  unsigned short* wh2   = (unsigned short*)(ws + 83677440);  // 19.2 MB
  unsigned short* w1t   = (unsigned short*)(ws + 102877440); // 98,304 B
  unsigned short* w2t   = (unsigned short*)(ws + 102975744); // 49,152 B

  prep_count_k<<<2 * NCH + 1635, 1024, 0, stream>>>(feat, W1, W2, ed1, ed2,
                                                    featb, w1t, w2t, ghist, done);
  scanb_k<<<2 * NB, 320, 0, stream>>>(ghist, btot, bbase, done);
  scatter_k<<<2 * NCH, 1024, 0, stream>>>(es1, ed1, es2, ed2, ghist, bbase, sorted);
  sortb_k<<<2 * NB, 512, 0, stream>>>(bbase, sorted, sorted2, offk, cntk);
  agg1_k<<<12500, 256, 0, stream>>>(offk, cntk, sorted2, (const uint2*)featb,
                                    (uint2*)s1m);
  gemm12_k<<<512, 512, 0, stream>>>(s1m, cntk, w1t, b1, w2t, b2, wh2);
  agg2f_k<<<12500, 256, 0, stream>>>(offk, cntk, sorted2, (const uint2*)wh2,
                                     (float*)d_out);
}

// Round 13
// 357.190 us; speedup vs baseline: 1.2013x; 1.2013x over previous
//
#include <hip/hip_runtime.h>

typedef __attribute__((ext_vector_type(8))) short short8;
typedef __attribute__((ext_vector_type(4))) float floatx4;

#define NCH 294         // chunks per layer
#define CH 8192         // edges per chunk
#define NB 196          // coarse buckets (1024 keys each)
#define NKP 200704      // padded key count (NB*1024)

__device__ __forceinline__ unsigned short f2bf(float f) {
  unsigned u = __float_as_uint(f);
  u += 0x7FFFu + ((u >> 16) & 1u);
  return (unsigned short)(u >> 16);
}
__device__ __forceinline__ float blo(unsigned x) { return __uint_as_float(x << 16); }
__device__ __forceinline__ float bhi(unsigned x) { return __uint_as_float(x & 0xFFFF0000u); }

// ---- fused prep (feat->bf16, W transposes) + per-chunk bucket histogram ----
__global__ __launch_bounds__(1024) void prep_count_k(
    const float* __restrict__ feat, const float* __restrict__ W1,
    const float* __restrict__ W2, const int* __restrict__ ed1,
    const int* __restrict__ ed2, unsigned short* __restrict__ featb,
    unsigned short* __restrict__ w1t, unsigned short* __restrict__ w2t,
    int* __restrict__ ghist) {
  __shared__ int h[NB];
  if (blockIdx.x < 2 * NCH) {            // count role
    int tid = threadIdx.x;
    int layer = blockIdx.x >= NCH;
    int c = blockIdx.x - layer * NCH;
    const int* ed = layer ? ed2 : ed1;
    if (tid < NB) h[tid] = 0;
    __syncthreads();
    int j0 = c * CH;
    for (int it = 0; it < CH / 1024; ++it) {
      int j = j0 + it * 1024 + tid;
      if (j < 2400000) atomicAdd(&h[(ed[j] * 4 + j / 800000) >> 10], 1);
    }
    __syncthreads();
    if (tid < NB) ghist[(layer * NB + tid) * NCH + c] = h[tid];
  } else {                               // prep role
    int tid = (blockIdx.x - 2 * NCH) * 1024 + threadIdx.x;
    if (tid < 1600000) {
      float4 v = ((const float4*)feat)[tid];
      ushort4 o;
      o.x = f2bf(v.x); o.y = f2bf(v.y); o.z = f2bf(v.z); o.w = f2bf(v.w);
      ((ushort4*)featb)[tid] = o;
    } else if (tid < 1600000 + 49152) {
      int t = tid - 1600000;
      int r = t >> 14, rem = t & 16383, n = rem >> 7, k = rem & 127;
      w1t[t] = f2bf(W1[(r << 14) + (k << 7) + n]);
    } else if (tid < 1600000 + 49152 + 24576) {
      int t = tid - 1649152;
      int r = t >> 13, rem = t & 8191, n = rem >> 7, k = rem & 127;
      w2t[t] = f2bf(W2[(r << 13) + (k << 6) + n]);
    }
  }
}

// ---- per-(layer,bucket) scan of 294 chunk counts -> gpre (counts kept) ----
__global__ __launch_bounds__(320) void scanb_k(const int* __restrict__ ghist,
                                               int* __restrict__ gpre,
                                               int* __restrict__ btot) {
  __shared__ int wsum[5];
  int t = threadIdx.x, lane = t & 63, w = t >> 6;
  int base = blockIdx.x * NCH;
  int v = (t < NCH) ? ghist[base + t] : 0;
  int inc = v;
#pragma unroll
  for (int o = 1; o < 64; o <<= 1) {
    int u = __shfl_up(inc, o);
    if (lane >= o) inc += u;
  }
  if (lane == 63) wsum[w] = inc;
  __syncthreads();
  int woff = 0;
#pragma unroll
  for (int k = 0; k < 5; ++k) if (k < w) woff += wsum[k];
  if (t < NCH) gpre[base + t] = woff + inc - v;
  if (t == 319) btot[blockIdx.x] = woff + inc;
}

// ---- single-wave scan of the 392 bucket totals -> bucket bases + sentinel ----
__global__ __launch_bounds__(64) void scanc_k(const int* __restrict__ btot,
                                              int* __restrict__ bbase) {
  int lane = threadIdx.x;
  int carry = 0;
  for (int g0 = 0; g0 < 448; g0 += 64) {
    int i = g0 + lane;
    int v = (i < 2 * NB) ? btot[i] : 0;
    int inc = v;
#pragma unroll
    for (int o = 1; o < 64; o <<= 1) {
      int u = __shfl_up(inc, o);
      if (lane >= o) inc += u;
    }
    if (i < 2 * NB) bbase[i] = carry + inc - v;
    carry += __shfl(inc, 63);
  }
  if (lane == 0) bbase[2 * NB] = carry;
}

// ---- LDS-staged scatter: bucket-sort whole 32KB chunk in LDS, then flush
// bucket-runs with consecutive lanes -> full-line coalesced global stores ----
__global__ __launch_bounds__(1024) void scatter_k(
    const int* __restrict__ es1, const int* __restrict__ ed1,
    const int* __restrict__ es2, const int* __restrict__ ed2,
    const int* __restrict__ ghist, const int* __restrict__ gpre,
    const int* __restrict__ bbase, unsigned* __restrict__ sorted) {
  __shared__ unsigned ent[CH];          // 32 KB
  __shared__ unsigned char bid[CH];     // 8 KB
  __shared__ int lstart[NB], lcur[NB], gb[NB];
  int tid = threadIdx.x;
  int layer = blockIdx.x >= NCH;
  int c = blockIdx.x - layer * NCH;
  const int* es = layer ? es2 : es1;
  const int* ed = layer ? ed2 : ed1;
  int rowb = layer * NB;
  if (tid < NB) {
    int idx = (rowb + tid) * NCH + c;
    lstart[tid] = ghist[idx];           // counts (temporarily)
    gb[tid] = bbase[rowb + tid] + gpre[idx];
  }
  __syncthreads();
  if (tid < 64) {                       // wave scan counts -> exclusive prefix
    int carry = 0;
    for (int g0 = 0; g0 < NB; g0 += 64) {
      int i = g0 + tid;
      int h = (i < NB) ? lstart[i] : 0;
      int inc = h;
#pragma unroll
      for (int o = 1; o < 64; o <<= 1) {
        int u = __shfl_up(inc, o);
        if (tid >= o) inc += u;
      }
      if (i < NB) {
        int e = carry + inc - h;
        lstart[i] = e;
        lcur[i] = e;
      }
      carry += __shfl(inc, 63);
    }
  }
  __syncthreads();
  int j0 = c * CH;
  int cn = 2400000 - j0;
  if (cn > CH) cn = CH;
  for (int it = 0; it < CH / 1024; ++it) {
    int jj = it * 1024 + tid;
    if (jj < cn) {
      int j = j0 + jj;
      int key = ed[j] * 4 + j / 800000;
      int b = key >> 10;
      int pos = atomicAdd(&lcur[b], 1);
      ent[pos] = (unsigned)es[j] | ((unsigned)(key & 1023) << 16);
      bid[pos] = (unsigned char)b;
    }
  }
  __syncthreads();
  for (int i = tid; i < cn; i += 1024) {
    int b = bid[i];
    sorted[gb[b] + (i - lstart[b])] = ent[i];
  }
}

// ---- per-bucket micro-sort: bucket-grouped -> key-sorted ushort srcs + off/cnt ----
__global__ __launch_bounds__(1024) void sortb_k(
    const int* __restrict__ bbase, const unsigned* __restrict__ sorted,
    unsigned short* __restrict__ sorted2, int* __restrict__ offk,
    int* __restrict__ cntk) {
  __shared__ int hist[1024], cur[1024];
  int tid = threadIdx.x;
  int layer = blockIdx.x >= NB;
  int b = blockIdx.x - layer * NB;
  int start = bbase[blockIdx.x];
  int end = bbase[blockIdx.x + 1];
  hist[tid] = 0;
  __syncthreads();
  for (int e = start + tid; e < end; e += 1024)
    atomicAdd(&hist[sorted[e] >> 16], 1);
  __syncthreads();
  if (tid < 64) {
    int carry = 0;
    for (int g0 = 0; g0 < 1024; g0 += 64) {
      int h = hist[g0 + tid];
      int inc = h;
#pragma unroll
      for (int o = 1; o < 64; o <<= 1) {
        int u = __shfl_up(inc, o);
        if (tid >= o) inc += u;
      }
      int excl = carry + inc - h;
      cur[g0 + tid] = excl;
      int lb = layer * NKP + (b << 10) + g0 + tid;
      offk[lb] = start + excl;
      cntk[lb] = h;
      carry += __shfl(inc, 63);
    }
  }
  __syncthreads();
  for (int e = start + tid; e < end; e += 1024) {
    unsigned v = sorted[e];
    int p = atomicAdd(&cur[v >> 16], 1);
    sorted2[start + p] = (unsigned short)(v & 0xFFFFu);
  }
}

// ---- layer-1 agg: wave per node, 2 edges per vmem instr (uint2/lane) ----
__global__ __launch_bounds__(256) void agg1_k(
    const int* __restrict__ offk, const int* __restrict__ cntk,
    const unsigned short* __restrict__ sorted2,
    const uint2* __restrict__ fb2, uint2* __restrict__ s1m2) {
  int lane = threadIdx.x & 63;
  int half = lane >> 5, l32 = lane & 31;
  int v = blockIdx.x * 4 + (threadIdx.x >> 6);
  if (v >= 50000) return;
  const uint2* fb = fb2 + l32;
#pragma unroll
  for (int r = 0; r < 3; ++r) {
    int key = v * 4 + r;
    int base = offk[key], n = cntk[key];
    float a0 = 0.f, a1 = 0.f, a2 = 0.f, a3 = 0.f;
    for (int jb = 0; jb < n; jb += 64) {
      int m = n - jb; if (m > 64) m = 64;
      int my = (lane < m) ? (int)sorted2[base + jb + lane] : 0;
      int k = 0;
      for (; k + 8 <= m; k += 8) {
        int i0 = __shfl(my, k + half);
        int i1 = __shfl(my, k + 2 + half);
        int i2 = __shfl(my, k + 4 + half);
        int i3 = __shfl(my, k + 6 + half);
        uint2 p0 = fb[i0 << 5], p1 = fb[i1 << 5];
        uint2 p2 = fb[i2 << 5], p3 = fb[i3 << 5];
        a0 += blo(p0.x) + blo(p1.x) + blo(p2.x) + blo(p3.x);
        a1 += bhi(p0.x) + bhi(p1.x) + bhi(p2.x) + bhi(p3.x);
        a2 += blo(p0.y) + blo(p1.y) + blo(p2.y) + blo(p3.y);
        a3 += bhi(p0.y) + bhi(p1.y) + bhi(p2.y) + bhi(p3.y);
      }
      for (; k + 2 <= m; k += 2) {
        int i0 = __shfl(my, k + half);
        uint2 p = fb[i0 << 5];
        a0 += blo(p.x); a1 += bhi(p.x); a2 += blo(p.y); a3 += bhi(p.y);
      }
      if (k < m) {
        int i0 = __shfl(my, k);
        if (half == 0) {
          uint2 p = fb[i0 << 5];
          a0 += blo(p.x); a1 += bhi(p.x); a2 += blo(p.y); a3 += bhi(p.y);
        }
      }
    }
    a0 += __shfl_xor(a0, 32); a1 += __shfl_xor(a1, 32);
    a2 += __shfl_xor(a2, 32); a3 += __shfl_xor(a3, 32);
    float inv = 1.0f / fmaxf((float)n, 1.0f);
    if (half == 0) {
      uint2 o;
      o.x = ((unsigned)f2bf(a1 * inv) << 16) | (unsigned)f2bf(a0 * inv);
      o.y = ((unsigned)f2bf(a3 * inv) << 16) | (unsigned)f2bf(a2 * inv);
      s1m2[(r * 50000 + v) * 32 + l32] = o;
    }
  }
}

// ---- fused GEMM1+GEMM2, persistent weights in registers, grid-stride M ----
__global__ __launch_bounds__(512) void gemm12_k(
    const unsigned short* __restrict__ s1m, const int* __restrict__ cntk,
    const unsigned short* __restrict__ w1t, const float* __restrict__ b1,
    const unsigned short* __restrict__ w2t, const float* __restrict__ b2,
    unsigned short* __restrict__ wh2) {
  __shared__ unsigned short hs[2][16 * 136];
  int lane = threadIdx.x & 63;
  int w = threadIdx.x >> 6;             // 0..7
  int m16 = lane & 15, kg = lane >> 4;
  int orow = kg << 2;

  short8 B1[12];
#pragma unroll
  for (int ks = 0; ks < 12; ++ks) {
    int r = ks >> 2;
    int k0 = ((ks & 3) << 5) + (kg << 3);
    int n = (w << 4) + m16;
    B1[ks] = *(const short8*)(w1t + (r << 14) + (n << 7) + k0);
  }
  int fa = w, fb = w + 8;
  int cola = (fa << 4) + m16, colb = (fb << 4) + m16;
  int ra = cola >> 6, c0a = cola & 63;
  int rb = colb >> 6, c0b = colb & 63;
  short8 B2a[4], B2b[4];
#pragma unroll
  for (int ks = 0; ks < 4; ++ks) {
    int k0 = (ks << 5) + (kg << 3);
    B2a[ks] = *(const short8*)(w2t + (ra << 13) + (c0a << 7) + k0);
    if (w < 4)
      B2b[ks] = *(const short8*)(w2t + (rb << 13) + (c0b << 7) + k0);
  }
  int col1 = (w << 4) + m16;
  float bb0 = b1[col1], bb1 = b1[128 + col1], bb2 = b1[256 + col1];
  float bva = b2[(ra << 6) + c0a];
  float bvb = (w < 4) ? b2[(rb << 6) + c0b] : 0.f;

  const floatx4 fzero = {0.f, 0.f, 0.f, 0.f};
  int p = 0;
  for (int t = blockIdx.x; t < 3125; t += 512) {
    int rbase = t << 4;
    int anode = rbase + m16;
    floatx4 acc1 = fzero;
#pragma unroll
    for (int ks = 0; ks < 12; ++ks) {
      int r = ks >> 2;
      int k0 = ((ks & 3) << 5) + (kg << 3);
      short8 af = *(const short8*)(s1m + ((r * 50000 + anode) << 7) + k0);
      acc1 = __builtin_amdgcn_mfma_f32_16x16x32_bf16(af, B1[ks], acc1, 0, 0, 0);
    }
#pragma unroll
    for (int reg = 0; reg < 4; ++reg) {
      int nd = rbase + orow + reg;
      float v = acc1[reg] + (cntk[nd * 4 + 0] ? bb0 : 0.f) +
                (cntk[nd * 4 + 1] ? bb1 : 0.f) + (cntk[nd * 4 + 2] ? bb2 : 0.f);
      v = (v >= 0.f) ? v : 0.01f * v;
      hs[p][(orow + reg) * 136 + col1] = f2bf(v);
    }
    __syncthreads();

    floatx4 acc2a = fzero, acc2b = fzero;
#pragma unroll
    for (int ks = 0; ks < 4; ++ks) {
      int k0 = (ks << 5) + (kg << 3);
      short8 af = *(const short8*)(&hs[p][m16 * 136 + k0]);
      acc2a = __builtin_amdgcn_mfma_f32_16x16x32_bf16(af, B2a[ks], acc2a, 0, 0, 0);
      if (w < 4)
        acc2b = __builtin_amdgcn_mfma_f32_16x16x32_bf16(af, B2b[ks], acc2b, 0, 0, 0);
    }
#pragma unroll
    for (int reg = 0; reg < 4; ++reg) {
      int nd = rbase + orow + reg;
      wh2[((ra * 50000 + nd) << 6) + c0a] = f2bf(acc2a[reg] + bva);
      if (w < 4)
        wh2[((rb * 50000 + nd) << 6) + c0b] = f2bf(acc2b[reg] + bvb);
    }
    p ^= 1;
  }
}

// ---- layer-2 agg + final: wave per node, 4 edges per vmem instr (uint2/16 lanes) ----
__global__ __launch_bounds__(256) void agg2f_k(
    const int* __restrict__ offk, const int* __restrict__ cntk,
    const unsigned short* __restrict__ sorted2,
    const uint2* __restrict__ wh2q, float* __restrict__ out) {
  int lane = threadIdx.x & 63;
  int q = lane >> 4, l16 = lane & 15;
  int v = blockIdx.x * 4 + (threadIdx.x >> 6);
  if (v >= 50000) return;
  const uint2* wb = wh2q + l16;
  float o0 = 0.f, o1 = 0.f, o2 = 0.f, o3 = 0.f;
#pragma unroll
  for (int r = 0; r < 3; ++r) {
    int key = NKP + v * 4 + r;
    int base = offk[key], n = cntk[key];
    const uint2* wbr = wb + ((r * 50000) << 4);
    float a0 = 0.f, a1 = 0.f, a2 = 0.f, a3 = 0.f;
    for (int jb = 0; jb < n; jb += 64) {
      int m = n - jb; if (m > 64) m = 64;
      int my = (lane < m) ? (int)sorted2[base + jb + lane] : 0;
      int k = 0;
      for (; k + 16 <= m; k += 16) {
        int i0 = __shfl(my, k + q);
        int i1 = __shfl(my, k + 4 + q);
        int i2 = __shfl(my, k + 8 + q);
        int i3 = __shfl(my, k + 12 + q);
        uint2 p0 = wbr[i0 << 4], p1 = wbr[i1 << 4];
        uint2 p2 = wbr[i2 << 4], p3 = wbr[i3 << 4];
        a0 += blo(p0.x) + blo(p1.x) + blo(p2.x) + blo(p3.x);
        a1 += bhi(p0.x) + bhi(p1.x) + bhi(p2.x) + bhi(p3.x);
        a2 += blo(p0.y) + blo(p1.y) + blo(p2.y) + blo(p3.y);
        a3 += bhi(p0.y) + bhi(p1.y) + bhi(p2.y) + bhi(p3.y);
      }
      for (; k + 4 <= m; k += 4) {
        uint2 p = wbr[__shfl(my, k + q) << 4];
        a0 += blo(p.x); a1 += bhi(p.x); a2 += blo(p.y); a3 += bhi(p.y);
      }
      if (k < m) {
        int rem = m - k;
        int i0 = __shfl(my, k + (q < rem ? q : 0));
        if (q < rem) {
          uint2 p = wbr[i0 << 4];
          a0 += blo(p.x); a1 += bhi(p.x); a2 += blo(p.y); a3 += bhi(p.y);
        }
      }
    }
    float inv = 1.0f / fmaxf((float)n, 1.0f);
    o0 += a0 * inv; o1 += a1 * inv; o2 += a2 * inv; o3 += a3 * inv;
  }
  o0 += __shfl_xor(o0, 16); o0 += __shfl_xor(o0, 32);
  o1 += __shfl_xor(o1, 16); o1 += __shfl_xor(o1, 32);
  o2 += __shfl_xor(o2, 16); o2 += __shfl_xor(o2, 32);
  o3 += __shfl_xor(o3, 16); o3 += __shfl_xor(o3, 32);
  if (q == 0) {
    float4 o; o.x = o0; o.y = o1; o.z = o2; o.w = o3;
    ((float4*)out)[(v << 4) + l16] = o;
  }
}

extern "C" void kernel_launch(void* const* d_in, const int* in_sizes, int n_in,
                              void* d_out, int out_size, void* d_ws, size_t ws_size,
                              hipStream_t stream) {
  const float* feat = (const float*)d_in[0];
  const float* W1   = (const float*)d_in[1];
  const float* b1   = (const float*)d_in[2];
  const float* W2   = (const float*)d_in[3];
  const float* b2   = (const float*)d_in[4];
  const int* es1 = (const int*)d_in[5];
  const int* ed1 = (const int*)d_in[6];
  const int* es2 = (const int*)d_in[7];
  const int* ed2 = (const int*)d_in[8];

  char* ws = (char*)d_ws;
  int* ghist           = (int*)(ws + 0);             // 460,992 B (counts)
  int* gpre            = (int*)(ws + 460992);        // 460,992 B (prefixes)
  int* btot            = (int*)(ws + 921984);        // 392 ints
  int* bbase           = (int*)(ws + 923552);        // 393 ints
  unsigned* sorted     = (unsigned*)(ws + 925184);   // 19.2 MB
  unsigned short* sorted2 = (unsigned short*)(ws + 20125184); // 9.6 MB
  int* offk            = (int*)(ws + 29725184);      // 2*200704 ints
  int* cntk            = (int*)(ws + 31330816);      // 2*200704 ints
  unsigned short* featb = (unsigned short*)(ws + 32936448);  // 12.8 MB
  unsigned short* s1m   = (unsigned short*)(ws + 45736448);  // 38.4 MB
  unsigned short* wh2   = (unsigned short*)(ws + 84136448);  // 19.2 MB
  unsigned short* w1t   = (unsigned short*)(ws + 103336448); // 98,304 B
  unsigned short* w2t   = (unsigned short*)(ws + 103434752); // 49,152 B

  prep_count_k<<<2 * NCH + 1635, 1024, 0, stream>>>(feat, W1, W2, ed1, ed2,
                                                    featb, w1t, w2t, ghist);
  scanb_k<<<2 * NB, 320, 0, stream>>>(ghist, gpre, btot);
  scanc_k<<<1, 64, 0, stream>>>(btot, bbase);
  scatter_k<<<2 * NCH, 1024, 0, stream>>>(es1, ed1, es2, ed2, ghist, gpre,
                                          bbase, sorted);
  sortb_k<<<2 * NB, 1024, 0, stream>>>(bbase, sorted, sorted2, offk, cntk);
  agg1_k<<<12500, 256, 0, stream>>>(offk, cntk, sorted2, (const uint2*)featb,
                                    (uint2*)s1m);
  gemm12_k<<<512, 512, 0, stream>>>(s1m, cntk, w1t, b1, w2t, b2, wh2);
  agg2f_k<<<12500, 256, 0, stream>>>(offk, cntk, sorted2, (const uint2*)wh2,
                                     (float*)d_out);
}